// Round 4
// baseline (2186.026 us; speedup 1.0000x reference)
//
#include <hip/hip_runtime.h>

// GINModel on MI355X (gfx950). Round 4.
// Theory: rounds 1-3 never ran our code (bf16-MFMA builtin operand-type
// compile failure + stale-.so fallback => stub behavior, bit-identical error).
// This round: fp16 internal storage + __builtin_amdgcn_mfma_f32_16x16x32_f16
// (V8h signature, stable), runtime detection of int32/int64 indices and
// bf16/fp32 float inputs, in_sizes-based weight-slot discovery.
// All accumulation in fp32.

typedef __attribute__((ext_vector_type(4))) float f32x4;
typedef __attribute__((ext_vector_type(8))) _Float16 f16x8;

__device__ __forceinline__ float h2f(unsigned short u) {
  _Float16 h; __builtin_memcpy(&h, &u, 2); return (float)h;
}
__device__ __forceinline__ unsigned short f2h16(float f) {
  _Float16 h = (_Float16)f; unsigned short u; __builtin_memcpy(&u, &h, 2); return u;
}
__device__ __forceinline__ unsigned short f2b(float f) {  // fp32 -> bf16 RNE
  union { float f; unsigned int i; } c; c.f = f;
  unsigned int x = c.i;
  return (unsigned short)((x + 0x7fffu + ((x >> 16) & 1u)) >> 16);
}
// dual-width input float load: wf32 ? fp32 : bf16
__device__ __forceinline__ float lin(const void* p, long long i, int wf32) {
  if (wf32) return ((const float*)p)[i];
  union { unsigned int i; float f; } c;
  c.i = ((unsigned int)((const unsigned short*)p)[i]) << 16;
  return c.f;
}
// dual-width index load: w64 ? int64 (LE low word) : int32
__device__ __forceinline__ int ldidx(const int* p, long long i, int w64) {
  return w64 ? p[2 * i] : p[i];
}

// flags[0]=w64, flags[1]=wf32
__global__ void detect_k(const int* __restrict__ edge, const unsigned short* __restrict__ xa,
                         int* __restrict__ flags) {
  if (threadIdx.x != 0 || blockIdx.x != 0) return;
  int nzOdd = 0;
  for (int t = 0; t < 256; t++) if (edge[2 * t + 1] != 0) nzOdd++;
  flags[0] = (nzOdd == 0) ? 1 : 0;
  int plaus = 0;
  for (int t = 0; t < 64; t++) {
    unsigned short w = xa[2 * t];
    int e = (w >> 7) & 0xFF;
    if (w == 0 || (e >= 0x70 && e <= 0x85)) plaus++;
  }
  flags[1] = (plaus < 32) ? 1 : 0;
}

__global__ void zero_i32_k(int* __restrict__ p, int n) {
  int i = blockIdx.x * blockDim.x + threadIdx.x;
  if (i < n) p[i] = 0;
}
__global__ void zero_f32_k(float* __restrict__ p, int n) {
  int i = blockIdx.x * blockDim.x + threadIdx.x;
  if (i < n) p[i] = 0.f;
}

// dual-width 256-element param slice -> fp32
__global__ void copy256_k(const void* __restrict__ src, int eoff, float* __restrict__ dst,
                          const int* __restrict__ flags) {
  dst[threadIdx.x] = lin(src, (long long)eoff + threadIdx.x, flags[1]);
}

// input (R x C, dual width) -> fp16 transposed (C x R)
__global__ void transpose_k(const void* __restrict__ src, unsigned short* __restrict__ dst,
                            int R, int C, const int* __restrict__ flags) {
  int wf32 = flags[1];
  __shared__ unsigned short t[32][33];
  int bx = blockIdx.x * 32, by = blockIdx.y * 32;
  int x = bx + threadIdx.x;
  for (int i = 0; i < 32; i += 8) {
    int y = by + threadIdx.y + i;
    if (y < R && x < C)
      t[threadIdx.y + i][threadIdx.x] = f2h16(lin(src, (long long)y * C + x, wf32));
  }
  __syncthreads();
  int x2 = by + threadIdx.x;
  for (int i = 0; i < 32; i += 8) {
    int y = bx + threadIdx.y + i;
    if (y < C && x2 < R) dst[(long long)y * R + x2] = t[threadIdx.x][threadIdx.y + i];
  }
}

__global__ void hist_k(const int* __restrict__ edge, int E, int* __restrict__ cnt,
                       const int* __restrict__ flags) {
  int w64 = flags[0];
  int e = blockIdx.x * blockDim.x + threadIdx.x;
  if (e < E) atomicAdd(&cnt[ldidx(edge, (long long)E + e, w64)], 1);
}

#define SCAN_CHUNK 1024
__global__ void scan1_k(const int* __restrict__ in, int* __restrict__ out,
                        int* __restrict__ partials, int n) {
  __shared__ int sh[256];
  int tid = threadIdx.x;
  int base = blockIdx.x * SCAN_CHUNK + tid * 4;
  int v[4]; int tsum = 0;
#pragma unroll
  for (int i = 0; i < 4; i++) { v[i] = (base + i < n) ? in[base + i] : 0; tsum += v[i]; }
  sh[tid] = tsum; __syncthreads();
  for (int off = 1; off < 256; off <<= 1) {
    int t = (tid >= off) ? sh[tid - off] : 0;
    __syncthreads();
    sh[tid] += t;
    __syncthreads();
  }
  int run = sh[tid] - tsum;
#pragma unroll
  for (int i = 0; i < 4; i++) { if (base + i < n) out[base + i] = run; run += v[i]; }
  if (tid == 255) partials[blockIdx.x] = sh[255];
}
__global__ void scan2_k(int* partials, int B) {
  __shared__ int sh[256];
  int tid = threadIdx.x;
  int orig = (tid < B) ? partials[tid] : 0;
  sh[tid] = orig; __syncthreads();
  for (int off = 1; off < 256; off <<= 1) {
    int t = (tid >= off) ? sh[tid - off] : 0;
    __syncthreads();
    sh[tid] += t;
    __syncthreads();
  }
  if (tid < B) partials[tid] = sh[tid] - orig;
}
__global__ void scan3_k(int* __restrict__ out, const int* __restrict__ partials,
                        int n, int total) {
  int base = blockIdx.x * SCAN_CHUNK + threadIdx.x * 4;
  int add = partials[blockIdx.x];
#pragma unroll
  for (int i = 0; i < 4; i++) { if (base + i < n) out[base + i] += add; }
  if (blockIdx.x == 0 && threadIdx.x == 0) out[n] = total;
}

__global__ void fill_k(const int* __restrict__ edge, int E, const int* __restrict__ rowptr,
                       int* __restrict__ cnt, int* __restrict__ colidx,
                       const int* __restrict__ flags) {
  int w64 = flags[0];
  int e = blockIdx.x * blockDim.x + threadIdx.x;
  if (e >= E) return;
  int s = ldidx(edge, e, w64);
  int d = ldidx(edge, (long long)E + e, w64);
  int p = atomicAdd(&cnt[d], 1);
  colidx[rowptr[d] + p] = s;
}

// layer-0 aggregation: reads input x (dual width), F=128 -> fp16 u. Wave/node.
__global__ void gather0_k(const void* __restrict__ x, const int* __restrict__ rowptr,
                          const int* __restrict__ colidx, unsigned short* __restrict__ u,
                          int Nn, const int* __restrict__ flags) {
  int wf32 = flags[1];
  int gid = blockIdx.x * blockDim.x + threadIdx.x;
  int node = gid >> 6;
  if (node >= Nn) return;
  int lane = gid & 63;
  float a0 = lin(x, (long long)node * 128 + lane * 2, wf32);
  float a1 = lin(x, (long long)node * 128 + lane * 2 + 1, wf32);
  int s = rowptr[node], e = rowptr[node + 1];
  for (int j = s; j < e; j++) {
    long long nb = colidx[j];
    a0 += lin(x, nb * 128 + lane * 2, wf32);
    a1 += lin(x, nb * 128 + lane * 2 + 1, wf32);
  }
  u[(long long)node * 128 + lane * 2]     = f2h16(a0);
  u[(long long)node * 128 + lane * 2 + 1] = f2h16(a1);
}
// layers 1..4 aggregation: internal fp16, F=256. Wave/node.
__global__ void gather_k(const unsigned short* __restrict__ h, const int* __restrict__ rowptr,
                         const int* __restrict__ colidx, unsigned short* __restrict__ u, int Nn) {
  int gid = blockIdx.x * blockDim.x + threadIdx.x;
  int node = gid >> 6;
  if (node >= Nn) return;
  int lane = gid & 63;
  float acc0, acc1, acc2, acc3;
  {
    uint2 raw = *(const uint2*)(h + (long long)node * 256 + lane * 4);
    acc0 = h2f(raw.x & 0xffff); acc1 = h2f(raw.x >> 16);
    acc2 = h2f(raw.y & 0xffff); acc3 = h2f(raw.y >> 16);
  }
  int s = rowptr[node], e = rowptr[node + 1];
  for (int j = s; j < e; j++) {
    long long nb = colidx[j];
    uint2 raw = *(const uint2*)(h + nb * 256 + lane * 4);
    acc0 += h2f(raw.x & 0xffff); acc1 += h2f(raw.x >> 16);
    acc2 += h2f(raw.y & 0xffff); acc3 += h2f(raw.y >> 16);
  }
  uint2 o;
  o.x = (unsigned int)f2h16(acc0) | ((unsigned int)f2h16(acc1) << 16);
  o.y = (unsigned int)f2h16(acc2) | ((unsigned int)f2h16(acc3) << 16);
  *(uint2*)(u + (long long)node * 256 + lane * 4) = o;
}

// MFMA fp16 GEMM: C(MxN=256) = act(A(MxK) @ W + bias_f32). Bt = W^T (256 x K).
// Tile 128x128, BK=32, 4 waves (2x2 of 64x64).
__global__ __launch_bounds__(256) void gemm_k(
    const unsigned short* __restrict__ A, const unsigned short* __restrict__ Bt,
    const float* __restrict__ bias, unsigned short* __restrict__ C,
    int M, int K, int relu) {
  const int N = 256;
  __shared__ __align__(16) unsigned short As[128 * 32];
  __shared__ __align__(16) unsigned short Bs[128 * 32];
  int m0 = blockIdx.x * 128, n0 = blockIdx.y * 128;
  int tid = threadIdx.x;
  int wave = tid >> 6, lane = tid & 63;
  int wm = (wave >> 1) * 64, wn = (wave & 1) * 64;
  int lrow = lane & 15, lq = lane >> 4;
  f32x4 acc[4][4] = {};
  int ktiles = K >> 5;
  for (int kt = 0; kt < ktiles; ++kt) {
    int kb = kt << 5;
    uint4 va[2], vb[2];
#pragma unroll
    for (int i = 0; i < 2; i++) {
      int j = tid + (i << 8);
      int row = m0 + (j >> 2);
      row = row < M ? row : M - 1;
      va[i] = *(const uint4*)(A + (long long)row * K + kb + ((j & 3) << 3));
      int nrow = n0 + (j >> 2);
      vb[i] = *(const uint4*)(Bt + (long long)nrow * K + kb + ((j & 3) << 3));
    }
    __syncthreads();
#pragma unroll
    for (int i = 0; i < 2; i++) {
      int j = tid + (i << 8);
      *(uint4*)(As + j * 8) = va[i];
      *(uint4*)(Bs + j * 8) = vb[i];
    }
    __syncthreads();
    f16x8 af[4], bf[4];
#pragma unroll
    for (int r = 0; r < 4; r++)
      af[r] = *(const f16x8*)(As + (wm + 16 * r + lrow) * 32 + lq * 8);
#pragma unroll
    for (int c = 0; c < 4; c++)
      bf[c] = *(const f16x8*)(Bs + (wn + 16 * c + lrow) * 32 + lq * 8);
#pragma unroll
    for (int r = 0; r < 4; r++)
#pragma unroll
      for (int c = 0; c < 4; c++)
        acc[r][c] = __builtin_amdgcn_mfma_f32_16x16x32_f16(af[r], bf[c], acc[r][c], 0, 0, 0);
  }
#pragma unroll
  for (int c = 0; c < 4; c++) {
    int col = n0 + wn + 16 * c + lrow;
    float bv = bias[col];
#pragma unroll
    for (int r = 0; r < 4; r++) {
      int rbase = m0 + wm + 16 * r + lq * 4;
#pragma unroll
      for (int i = 0; i < 4; i++) {
        int row = rbase + i;
        if (row < M) {
          float v = acc[r][c][i] + bv;
          if (relu) v = fmaxf(v, 0.f);
          C[(long long)row * N + col] = f2h16(v);
        }
      }
    }
  }
}

__global__ void bn_stats_k(const unsigned short* __restrict__ v, float* __restrict__ gsum,
                           float* __restrict__ gsq, int Nn) {
  int f = threadIdx.x;
  float s = 0.f, q = 0.f;
  for (int r = blockIdx.x; r < Nn; r += gridDim.x) {
    float x = h2f(v[(long long)r * 256 + f]);
    s += x; q += x * x;
  }
  atomicAdd(&gsum[f], s);
  atomicAdd(&gsq[f], q);
}
__global__ void bn_finalize_k(const float* __restrict__ gsum, const float* __restrict__ gsq,
                              const float* __restrict__ gamma, const float* __restrict__ beta,
                              int Nn, float* __restrict__ scale, float* __restrict__ shift) {
  int f = threadIdx.x;
  float inv = 1.f / (float)Nn;
  float mean = gsum[f] * inv;
  float var = fmaxf(gsq[f] * inv - mean * mean, 0.f);
  float sc = gamma[f] * rsqrtf(var + 1e-5f);
  scale[f] = sc;
  shift[f] = beta[f] - mean * sc;
}
__global__ void bn_apply_k(const unsigned short* __restrict__ v, const float* __restrict__ scale,
                           const float* __restrict__ shift, unsigned short* __restrict__ h, int Nn) {
  int f = threadIdx.x;
  float sc = scale[f], sh = shift[f];
  for (int r = blockIdx.x; r < Nn; r += gridDim.x) {
    long long idx = (long long)r * 256 + f;
    h[idx] = f2h16(fmaxf(h2f(v[idx]) * sc + sh, 0.f));
  }
}

__global__ void graph_bounds_k(const int* __restrict__ b, int Nn, int G,
                               int* __restrict__ gstart, const int* __restrict__ flags) {
  int w64 = flags[0];
  int g = blockIdx.x * blockDim.x + threadIdx.x;
  if (g > G) return;
  int lo = 0, hi = Nn;
  while (lo < hi) {
    int mid = (lo + hi) >> 1;
    if (ldidx(b, mid, w64) < g) lo = mid + 1; else hi = mid;
  }
  gstart[g] = lo;
}
__global__ void pool_k(const unsigned short* __restrict__ h, const int* __restrict__ gstart,
                       unsigned short* __restrict__ gout) {
  int g = blockIdx.x, f = threadIdx.x;
  int s = gstart[g], e = gstart[g + 1];
  float acc = 0.f;
  for (int r = s; r < e; r++) acc += h2f(h[(long long)r * 256 + f]);
  gout[(long long)g * 256 + f] = f2h16(acc / fmaxf((float)(e - s), 1.f));
}
__global__ void pred2_k(const unsigned short* __restrict__ p1, const void* __restrict__ Wp2,
                        const void* __restrict__ bp2, void* __restrict__ out, int G,
                        const int* __restrict__ flags) {
  int wf32 = flags[1];
  int idx = blockIdx.x * blockDim.x + threadIdx.x;
  if (idx >= G * 12) return;
  int g = idx / 12, t = idx - g * 12;
  float acc = lin(bp2, t, wf32);
  const unsigned short* row = p1 + (long long)g * 256;
  for (int k = 0; k < 256; k++) acc += h2f(row[k]) * lin(Wp2, k * 12 + t, wf32);
  if (wf32) ((float*)out)[idx] = acc;
  else      ((unsigned short*)out)[idx] = f2b(acc);
}

extern "C" void kernel_launch(void* const* d_in, const int* in_sizes, int n_in,
                              void* d_out, int out_size, void* d_ws, size_t ws_size,
                              hipStream_t stream) {
  int wb = -1;
  for (int i = 3; i + 15 < n_in; i++) {
    if (in_sizes[i] == 32768 && in_sizes[i + 1] == 256 && in_sizes[i + 2] == 65536 &&
        in_sizes[i + 3] == 256 && in_sizes[i + 4] == 256 && in_sizes[i + 5] == 256 &&
        in_sizes[i + 6] == 262144) { wb = i; break; }
  }
  if (wb < 0) wb = (n_in >= 20) ? 4 : 3;

  const void* x      = d_in[0];
  const int*  edge   = (const int*)d_in[1];
  const int*  batch  = (const int*)d_in[2];
  const void* W1_0   = d_in[wb + 0];
  const void* b1_0   = d_in[wb + 1];
  const void* W2_0   = d_in[wb + 2];
  const void* b2_0   = d_in[wb + 3];
  const void* gamma0 = d_in[wb + 4];
  const void* beta0  = d_in[wb + 5];
  const void* W1s    = d_in[wb + 6];
  const void* b1s    = d_in[wb + 7];
  const void* W2s    = d_in[wb + 8];
  const void* b2s    = d_in[wb + 9];
  const void* gammas = d_in[wb + 10];
  const void* betas  = d_in[wb + 11];
  const void* Wp1    = d_in[wb + 12];
  const void* bp1    = d_in[wb + 13];
  const void* Wp2    = d_in[wb + 14];
  const void* bp2    = d_in[wb + 15];

  const int N = in_sizes[0] / 128;
  const int E = in_sizes[1] / 2;
  const int G = out_size / 12;
  const int H = 256;

  char* w = (char*)d_ws;
  size_t off = 0;
  auto alloc = [&](size_t bytes) -> char* {
    char* p = w + off;
    off += (bytes + 255) & ~(size_t)255;
    return p;
  };
  unsigned short* bufX  = (unsigned short*)alloc((size_t)N * H * 2);
  unsigned short* bufZ  = (unsigned short*)alloc((size_t)N * H * 2);
  unsigned short* w1_0t = (unsigned short*)alloc((size_t)128 * 256 * 2);
  unsigned short* w2_0t = (unsigned short*)alloc((size_t)256 * 256 * 2);
  unsigned short* w1st  = (unsigned short*)alloc((size_t)4 * 256 * 256 * 2);
  unsigned short* w2st  = (unsigned short*)alloc((size_t)4 * 256 * 256 * 2);
  unsigned short* wp1t  = (unsigned short*)alloc((size_t)256 * 256 * 2);
  int*   rowptr   = (int*)alloc((size_t)(N + 1) * 4);
  int*   cnt      = (int*)alloc((size_t)N * 4);
  int*   colidx   = (int*)alloc((size_t)E * 4);
  int*   partials = (int*)alloc(1024 * 4);
  float* gsum     = (float*)alloc(256 * 4);
  float* gsq      = (float*)alloc(256 * 4);
  float* bnscale  = (float*)alloc(256 * 4);
  float* bnshift  = (float*)alloc(256 * 4);
  float* pg       = (float*)alloc(256 * 4);
  float* pb       = (float*)alloc(256 * 4);
  float* pb1      = (float*)alloc(256 * 4);
  float* pb2      = (float*)alloc(256 * 4);
  int*   gstart   = (int*)alloc((size_t)(G + 1) * 4);
  int*   flags    = (int*)alloc(256);
  unsigned short* gpool = (unsigned short*)alloc((size_t)G * H * 2);
  unsigned short* p1    = (unsigned short*)alloc((size_t)G * H * 2);
  (void)ws_size; (void)n_in;

  detect_k<<<1, 64, 0, stream>>>(edge, (const unsigned short*)x, flags);

  // weight transposes -> fp16 (NxK). Source element offsets handled inside
  // transpose via element indexing, so pass base pointers + element offset
  // by pointer arithmetic only when width known... for stacked W1s/W2s we
  // avoid host-side width assumptions by calling transpose with an element
  // offset folded into a shifted source pointer in BOTH possible widths:
  // instead, transpose reads lin(src, y*C+x) so we pass a separate kernel
  // call per layer with src advanced by i*65536 ELEMENTS — done on device by
  // an extra offset argument below. Simplest: copy256-style offset param.
  dim3 tb(32, 8);
  // transpose with element offset: reuse transpose_k by passing shifted
  // pointers for BOTH widths is impossible host-side; so transpose_k gains
  // nothing — we instead call a thin wrapper kernel with offset:
  // (implemented by passing eoff through the R*C index math)
  // For simplicity we give transpose_k an extra element offset via C pointer:
  // just launch with src = base and add i*65536 inside by an offset arg.
  // --- offset-aware launches ---
  auto transpose = [&](const void* src, long long eoff, unsigned short* dst, int R, int C) {
    // wrap: temporary kernel-level offset via copy into the lin index:
    // we use a dedicated kernel below.
    extern __global__ void transpose_off_k(const void*, long long, unsigned short*, int, int, const int*);
    transpose_off_k<<<dim3((C + 31) / 32, (R + 31) / 32), tb, 0, stream>>>(src, eoff, dst, R, C, flags);
  };
  transpose(W1_0, 0, w1_0t, 128, 256);
  transpose(W2_0, 0, w2_0t, 256, 256);
  for (int i = 0; i < 4; i++) {
    transpose(W1s, (long long)i * 65536, w1st + i * 65536, 256, 256);
    transpose(W2s, (long long)i * 65536, w2st + i * 65536, 256, 256);
  }
  transpose(Wp1, 0, wp1t, 256, 256);

  // bias/gamma/beta slices -> fp32
  copy256_k<<<1, 256, 0, stream>>>(b1_0,   0, pb1, flags);  // layer-0 b1 (reused per layer)
  copy256_k<<<1, 256, 0, stream>>>(b2_0,   0, pb2, flags);
  copy256_k<<<1, 256, 0, stream>>>(gamma0, 0, pg,  flags);
  copy256_k<<<1, 256, 0, stream>>>(beta0,  0, pb,  flags);

  // CSR build
  zero_i32_k<<<(N + 255) / 256, 256, 0, stream>>>(cnt, N);
  hist_k<<<(E + 255) / 256, 256, 0, stream>>>(edge, E, cnt, flags);
  int NB = (N + SCAN_CHUNK - 1) / SCAN_CHUNK;
  scan1_k<<<NB, 256, 0, stream>>>(cnt, rowptr, partials, N);
  scan2_k<<<1, 256, 0, stream>>>(partials, NB);
  scan3_k<<<NB, 256, 0, stream>>>(rowptr, partials, N, E);
  zero_i32_k<<<(N + 255) / 256, 256, 0, stream>>>(cnt, N);
  fill_k<<<(E + 255) / 256, 256, 0, stream>>>(edge, E, rowptr, cnt, colidx, flags);
  graph_bounds_k<<<(G + 1 + 255) / 256, 256, 0, stream>>>(batch, N, G, gstart, flags);

  auto gemm = [&](const unsigned short* A, const unsigned short* Bt, const float* bias,
                  unsigned short* Cq, int M, int K, int relu) {
    gemm_k<<<dim3((M + 127) / 128, 2), 256, 0, stream>>>(A, Bt, bias, Cq, M, K, relu);
  };
  auto bnorm = [&]() {
    zero_f32_k<<<1, 256, 0, stream>>>(gsum, 256);
    zero_f32_k<<<1, 256, 0, stream>>>(gsq, 256);
    bn_stats_k<<<256, 256, 0, stream>>>(bufX, gsum, gsq, N);
    bn_finalize_k<<<1, 256, 0, stream>>>(gsum, gsq, pg, pb, N, bnscale, bnshift);
    bn_apply_k<<<2048, 256, 0, stream>>>(bufX, bnscale, bnshift, bufZ, N);
  };

  // layer 0
  gather0_k<<<(N * 64 + 255) / 256, 256, 0, stream>>>(x, rowptr, colidx, bufX, N, flags);
  gemm(bufX, w1_0t, pb1, bufZ, N, 128, 1);
  gemm(bufZ, w2_0t, pb2, bufX, N, 256, 0);
  bnorm();
  // layers 1..4
  for (int i = 0; i < 4; i++) {
    copy256_k<<<1, 256, 0, stream>>>(b1s,    i * 256, pb1, flags);
    copy256_k<<<1, 256, 0, stream>>>(b2s,    i * 256, pb2, flags);
    copy256_k<<<1, 256, 0, stream>>>(gammas, i * 256, pg,  flags);
    copy256_k<<<1, 256, 0, stream>>>(betas,  i * 256, pb,  flags);
    gather_k<<<(N * 64 + 255) / 256, 256, 0, stream>>>(bufZ, rowptr, colidx, bufX, N);
    gemm(bufX, w1st + i * 65536, pb1, bufZ, N, 256, 1);
    gemm(bufZ, w2st + i * 65536, pb2, bufX, N, 256, 0);
    bnorm();
  }

  pool_k<<<G, 256, 0, stream>>>(bufZ, gstart, gpool);
  copy256_k<<<1, 256, 0, stream>>>(bp1, 0, pb1, flags);
  gemm(gpool, wp1t, pb1, p1, G, 256, 1);
  pred2_k<<<(G * 12 + 255) / 256, 256, 0, stream>>>(p1, Wp2, bp2, d_out, G, flags);
}

// offset-aware transpose: input (R x C at element offset eoff, dual width)
// -> fp16 transposed (C x R)
__global__ void transpose_off_k(const void* __restrict__ src, long long eoff,
                                unsigned short* __restrict__ dst, int R, int C,
                                const int* __restrict__ flags) {
  int wf32 = flags[1];
  __shared__ unsigned short t[32][33];
  int bx = blockIdx.x * 32, by = blockIdx.y * 32;
  int x = bx + threadIdx.x;
  for (int i = 0; i < 32; i += 8) {
    int y = by + threadIdx.y + i;
    if (y < R && x < C)
      t[threadIdx.y + i][threadIdx.x] = f2h16(lin(src, eoff + (long long)y * C + x, wf32));
  }
  __syncthreads();
  int x2 = by + threadIdx.x;
  for (int i = 0; i < 32; i += 8) {
    int y = bx + threadIdx.y + i;
    if (y < C && x2 < R) dst[(long long)y * R + x2] = t[threadIdx.x][threadIdx.y + i];
  }
}

// Round 5
// 1144.969 us; speedup vs baseline: 1.9092x; 1.9092x over previous
//
#include <hip/hip_runtime.h>

// GINModel on MI355X (gfx950). Round 5: fuse BN+ReLU into gather/pool
// (removes bn_apply), fast vectorized bn_stats, GEMM K-tile prefetch,
// merged per-layer param prep. fp16 internal storage, fp32 accumulation,
// dual-width (bf16/fp32, int32/int64) input hardening retained.

typedef __attribute__((ext_vector_type(4))) float f32x4;
typedef __attribute__((ext_vector_type(8))) _Float16 f16x8;

__device__ __forceinline__ float h2f(unsigned short u) {
  _Float16 h; __builtin_memcpy(&h, &u, 2); return (float)h;
}
__device__ __forceinline__ unsigned short f2h16(float f) {
  _Float16 h = (_Float16)f; unsigned short u; __builtin_memcpy(&u, &h, 2); return u;
}
__device__ __forceinline__ unsigned short f2b(float f) {  // fp32 -> bf16 RNE
  union { float f; unsigned int i; } c; c.f = f;
  unsigned int x = c.i;
  return (unsigned short)((x + 0x7fffu + ((x >> 16) & 1u)) >> 16);
}
__device__ __forceinline__ float lin(const void* p, long long i, int wf32) {
  if (wf32) return ((const float*)p)[i];
  union { unsigned int i; float f; } c;
  c.i = ((unsigned int)((const unsigned short*)p)[i]) << 16;
  return c.f;
}
__device__ __forceinline__ int ldidx(const int* p, long long i, int w64) {
  return w64 ? p[2 * i] : p[i];
}

// flags[0]=w64 (int64 indices), flags[1]=wf32 (fp32 floats)
__global__ void detect_k(const int* __restrict__ edge, const unsigned short* __restrict__ xa,
                         int* __restrict__ flags) {
  if (threadIdx.x != 0 || blockIdx.x != 0) return;
  int nzOdd = 0;
  for (int t = 0; t < 256; t++) if (edge[2 * t + 1] != 0) nzOdd++;
  flags[0] = (nzOdd == 0) ? 1 : 0;
  int plaus = 0;
  for (int t = 0; t < 64; t++) {
    unsigned short w = xa[2 * t];
    int e = (w >> 7) & 0xFF;
    if (w == 0 || (e >= 0x70 && e <= 0x85)) plaus++;
  }
  flags[1] = (plaus < 32) ? 1 : 0;
}

__global__ void zero_i32_k(int* __restrict__ p, int n) {
  int i = blockIdx.x * blockDim.x + threadIdx.x;
  if (i < n) p[i] = 0;
}

// per-layer prep: slice 4x256 params to fp32 + zero BN accumulators (512 f32)
__global__ void prep_k(const void* __restrict__ b1, const void* __restrict__ b2,
                       const void* __restrict__ gm, const void* __restrict__ bt, int eoff,
                       float* __restrict__ pb1, float* __restrict__ pb2,
                       float* __restrict__ pg, float* __restrict__ pb,
                       float* __restrict__ gsum, const int* __restrict__ flags) {
  int wf32 = flags[1], t = threadIdx.x;
  pb1[t] = lin(b1, (long long)eoff + t, wf32);
  pb2[t] = lin(b2, (long long)eoff + t, wf32);
  pg[t]  = lin(gm, (long long)eoff + t, wf32);
  pb[t]  = lin(bt, (long long)eoff + t, wf32);
  gsum[t] = 0.f; gsum[256 + t] = 0.f;
}
__global__ void copy256_k(const void* __restrict__ src, int eoff, float* __restrict__ dst,
                          const int* __restrict__ flags) {
  dst[threadIdx.x] = lin(src, (long long)eoff + threadIdx.x, flags[1]);
}

// input (R x C at element offset, dual width) -> fp16 transposed (C x R)
__global__ void transpose_off_k(const void* __restrict__ src, long long eoff,
                                unsigned short* __restrict__ dst, int R, int C,
                                const int* __restrict__ flags) {
  int wf32 = flags[1];
  __shared__ unsigned short t[32][33];
  int bx = blockIdx.x * 32, by = blockIdx.y * 32;
  int x = bx + threadIdx.x;
  for (int i = 0; i < 32; i += 8) {
    int y = by + threadIdx.y + i;
    if (y < R && x < C)
      t[threadIdx.y + i][threadIdx.x] = f2h16(lin(src, eoff + (long long)y * C + x, wf32));
  }
  __syncthreads();
  int x2 = by + threadIdx.x;
  for (int i = 0; i < 32; i += 8) {
    int y = bx + threadIdx.y + i;
    if (y < C && x2 < R) dst[(long long)y * R + x2] = t[threadIdx.x][threadIdx.y + i];
  }
}

// ---------------- CSR ----------------
__global__ void hist_k(const int* __restrict__ edge, int E, int* __restrict__ cnt,
                       const int* __restrict__ flags) {
  int w64 = flags[0];
  int e = blockIdx.x * blockDim.x + threadIdx.x;
  if (e < E) atomicAdd(&cnt[ldidx(edge, (long long)E + e, w64)], 1);
}
#define SCAN_CHUNK 1024
__global__ void scan1_k(const int* __restrict__ in, int* __restrict__ out,
                        int* __restrict__ partials, int n) {
  __shared__ int sh[256];
  int tid = threadIdx.x;
  int base = blockIdx.x * SCAN_CHUNK + tid * 4;
  int v[4]; int tsum = 0;
#pragma unroll
  for (int i = 0; i < 4; i++) { v[i] = (base + i < n) ? in[base + i] : 0; tsum += v[i]; }
  sh[tid] = tsum; __syncthreads();
  for (int off = 1; off < 256; off <<= 1) {
    int t = (tid >= off) ? sh[tid - off] : 0;
    __syncthreads();
    sh[tid] += t;
    __syncthreads();
  }
  int run = sh[tid] - tsum;
#pragma unroll
  for (int i = 0; i < 4; i++) { if (base + i < n) out[base + i] = run; run += v[i]; }
  if (tid == 255) partials[blockIdx.x] = sh[255];
}
__global__ void scan2_k(int* partials, int B) {
  __shared__ int sh[256];
  int tid = threadIdx.x;
  int orig = (tid < B) ? partials[tid] : 0;
  sh[tid] = orig; __syncthreads();
  for (int off = 1; off < 256; off <<= 1) {
    int t = (tid >= off) ? sh[tid - off] : 0;
    __syncthreads();
    sh[tid] += t;
    __syncthreads();
  }
  if (tid < B) partials[tid] = sh[tid] - orig;
}
__global__ void scan3_k(int* __restrict__ out, const int* __restrict__ partials,
                        int n, int total) {
  int base = blockIdx.x * SCAN_CHUNK + threadIdx.x * 4;
  int add = partials[blockIdx.x];
#pragma unroll
  for (int i = 0; i < 4; i++) { if (base + i < n) out[base + i] += add; }
  if (blockIdx.x == 0 && threadIdx.x == 0) out[n] = total;
}
__global__ void fill_k(const int* __restrict__ edge, int E, const int* __restrict__ rowptr,
                       int* __restrict__ cnt, int* __restrict__ colidx,
                       const int* __restrict__ flags) {
  int w64 = flags[0];
  int e = blockIdx.x * blockDim.x + threadIdx.x;
  if (e >= E) return;
  int s = ldidx(edge, e, w64);
  int d = ldidx(edge, (long long)E + e, w64);
  int p = atomicAdd(&cnt[d], 1);
  colidx[rowptr[d] + p] = s;
}
__global__ void graph_bounds_k(const int* __restrict__ b, int Nn, int G,
                               int* __restrict__ gstart, const int* __restrict__ flags) {
  int w64 = flags[0];
  int g = blockIdx.x * blockDim.x + threadIdx.x;
  if (g > G) return;
  int lo = 0, hi = Nn;
  while (lo < hi) {
    int mid = (lo + hi) >> 1;
    if (ldidx(b, mid, w64) < g) lo = mid + 1; else hi = mid;
  }
  gstart[g] = lo;
}

// x (dual width) -> fp16
__global__ void convert_k(const void* __restrict__ x, unsigned short* __restrict__ xh,
                          long long n, const int* __restrict__ flags) {
  int wf32 = flags[1];
  long long base = ((long long)blockIdx.x * blockDim.x + threadIdx.x) * 4;
  if (base >= n) return;
#pragma unroll
  for (int k = 0; k < 4; k++) xh[base + k] = f2h16(lin(x, base + k, wf32));
}

// fused aggregation: u[i] = hn(i) + sum_{j in nbrs(i)} hn(j)
// hn = APPLY ? relu(v*scale+shift) : v.  LPN lanes per node, 8 fp16 per lane.
template <int LPN, int APPLY>
__global__ void gather_fused_k(const unsigned short* __restrict__ src,
                               const float* __restrict__ scale, const float* __restrict__ shift,
                               const int* __restrict__ rowptr, const int* __restrict__ colidx,
                               unsigned short* __restrict__ u, int Nn) {
  const int F = LPN * 8;
  int gid = blockIdx.x * blockDim.x + threadIdx.x;
  int node = gid / LPN;
  if (node >= Nn) return;
  int fb = (gid % LPN) * 8;
  float sc[8], sh[8];
  if (APPLY) {
#pragma unroll
    for (int k = 0; k < 8; k++) { sc[k] = scale[fb + k]; sh[k] = shift[fb + k]; }
  }
  float acc[8];
  {
    uint4 raw = *(const uint4*)(src + (long long)node * F + fb);
    unsigned int ws[4] = {raw.x, raw.y, raw.z, raw.w};
#pragma unroll
    for (int k = 0; k < 8; k++) {
      float xv = h2f((unsigned short)((ws[k >> 1] >> ((k & 1) * 16)) & 0xffff));
      acc[k] = APPLY ? fmaxf(xv * sc[k] + sh[k], 0.f) : xv;
    }
  }
  int s = rowptr[node], e = rowptr[node + 1];
  for (int j = s; j < e; j++) {
    long long nb = colidx[j];
    uint4 raw = *(const uint4*)(src + nb * F + fb);
    unsigned int ws[4] = {raw.x, raw.y, raw.z, raw.w};
#pragma unroll
    for (int k = 0; k < 8; k++) {
      float xv = h2f((unsigned short)((ws[k >> 1] >> ((k & 1) * 16)) & 0xffff));
      acc[k] += APPLY ? fmaxf(xv * sc[k] + sh[k], 0.f) : xv;
    }
  }
  uint4 o;
  unsigned int wo[4];
#pragma unroll
  for (int p = 0; p < 4; p++)
    wo[p] = (unsigned int)f2h16(acc[2 * p]) | ((unsigned int)f2h16(acc[2 * p + 1]) << 16);
  o.x = wo[0]; o.y = wo[1]; o.z = wo[2]; o.w = wo[3];
  *(uint4*)(u + (long long)node * F + fb) = o;
}

// MFMA fp16 GEMM with K-tile register prefetch.
// C(MxN=256) = act(A(MxK) @ W + bias_f32); Bt = W^T (256 x K).
// Tile 128x128, BK=32, 4 waves (2x2 of 64x64).
__global__ __launch_bounds__(256) void gemm_k(
    const unsigned short* __restrict__ A, const unsigned short* __restrict__ Bt,
    const float* __restrict__ bias, unsigned short* __restrict__ C,
    int M, int K, int relu) {
  const int N = 256;
  __shared__ __align__(16) unsigned short As[128 * 32];
  __shared__ __align__(16) unsigned short Bs[128 * 32];
  int m0 = blockIdx.x * 128, n0 = blockIdx.y * 128;
  int tid = threadIdx.x;
  int wave = tid >> 6, lane = tid & 63;
  int wm = (wave >> 1) * 64, wn = (wave & 1) * 64;
  int lrow = lane & 15, lq = lane >> 4;
  f32x4 acc[4][4] = {};
  int ktiles = K >> 5;
  int arow = m0 + (tid >> 2);          arow = arow < M ? arow : M - 1;
  int arow2 = m0 + ((tid + 256) >> 2); arow2 = arow2 < M ? arow2 : M - 1;
  int acol = (tid & 3) << 3;
  const unsigned short* pa0 = A + (long long)arow * K + acol;
  const unsigned short* pa1 = A + (long long)arow2 * K + acol;
  const unsigned short* pq0 = Bt + (long long)(n0 + (tid >> 2)) * K + acol;
  const unsigned short* pq1 = Bt + (long long)(n0 + ((tid + 256) >> 2)) * K + acol;
  uint4 va0 = *(const uint4*)pa0, va1 = *(const uint4*)pa1;
  uint4 vb0 = *(const uint4*)pq0, vb1 = *(const uint4*)pq1;
  for (int kt = 0; kt < ktiles; ++kt) {
    __syncthreads();
    *(uint4*)(As + tid * 8) = va0;
    *(uint4*)(As + (tid + 256) * 8) = va1;
    *(uint4*)(Bs + tid * 8) = vb0;
    *(uint4*)(Bs + (tid + 256) * 8) = vb1;
    __syncthreads();
    f16x8 af[4], bf[4];
#pragma unroll
    for (int r = 0; r < 4; r++)
      af[r] = *(const f16x8*)(As + (wm + 16 * r + lrow) * 32 + lq * 8);
#pragma unroll
    for (int c = 0; c < 4; c++)
      bf[c] = *(const f16x8*)(Bs + (wn + 16 * c + lrow) * 32 + lq * 8);
    if (kt + 1 < ktiles) {  // prefetch next K-tile; overlaps with MFMA below
      int kb = (kt + 1) << 5;
      va0 = *(const uint4*)(pa0 + kb); va1 = *(const uint4*)(pa1 + kb);
      vb0 = *(const uint4*)(pq0 + kb); vb1 = *(const uint4*)(pq1 + kb);
    }
#pragma unroll
    for (int r = 0; r < 4; r++)
#pragma unroll
      for (int c = 0; c < 4; c++)
        acc[r][c] = __builtin_amdgcn_mfma_f32_16x16x32_f16(af[r], bf[c], acc[r][c], 0, 0, 0);
  }
#pragma unroll
  for (int c = 0; c < 4; c++) {
    int col = n0 + wn + 16 * c + lrow;
    float bv = bias[col];
#pragma unroll
    for (int r = 0; r < 4; r++) {
      int rbase = m0 + wm + 16 * r + lq * 4;
#pragma unroll
      for (int i = 0; i < 4; i++) {
        int row = rbase + i;
        if (row < M) {
          float v = acc[r][c][i] + bv;
          if (relu) v = fmaxf(v, 0.f);
          C[(long long)row * N + col] = f2h16(v);
        }
      }
    }
  }
}

// fast BN stats: uint4 loads, 8 rows/block-step, LDS tree reduce, 2 atomics/thread.
// gsum layout: [0:256)=sum, [256:512)=sumsq. Zeroed by prep_k.
__global__ __launch_bounds__(256) void bn_stats_k(const unsigned short* __restrict__ v,
                                                  float* __restrict__ gsum, int Nn) {
  __shared__ float sh[4096];
  int tid = threadIdx.x;
  int chunk = tid & 31, rsub = tid >> 5;
  int fb = chunk * 8;
  float s[8] = {}, q[8] = {};
  for (int r = blockIdx.x * 8 + rsub; r < Nn; r += gridDim.x * 8) {
    uint4 raw = *(const uint4*)(v + (long long)r * 256 + fb);
    unsigned int ws[4] = {raw.x, raw.y, raw.z, raw.w};
#pragma unroll
    for (int k = 0; k < 8; k++) {
      float xv = h2f((unsigned short)((ws[k >> 1] >> ((k & 1) * 16)) & 0xffff));
      s[k] += xv; q[k] += xv * xv;
    }
  }
#pragma unroll
  for (int k = 0; k < 8; k++) {
    sh[rsub * 256 + fb + k] = s[k];
    sh[2048 + rsub * 256 + fb + k] = q[k];
  }
  __syncthreads();
  float ts = 0.f, tq = 0.f;
#pragma unroll
  for (int r = 0; r < 8; r++) { ts += sh[r * 256 + tid]; tq += sh[2048 + r * 256 + tid]; }
  atomicAdd(&gsum[tid], ts);
  atomicAdd(&gsum[256 + tid], tq);
}
__global__ void bn_finalize_k(const float* __restrict__ gsum,
                              const float* __restrict__ pg, const float* __restrict__ pb,
                              int Nn, float* __restrict__ scale, float* __restrict__ shift) {
  int f = threadIdx.x;
  float inv = 1.f / (float)Nn;
  float mean = gsum[f] * inv;
  float var = fmaxf(gsum[256 + f] * inv - mean * mean, 0.f);
  float sc = pg[f] * rsqrtf(var + 1e-5f);
  scale[f] = sc;
  shift[f] = pb[f] - mean * sc;
}

// fused pool: mean over graph rows of relu(v*sc+sh)
__global__ void pool_fused_k(const unsigned short* __restrict__ v, const float* __restrict__ scale,
                             const float* __restrict__ shift, const int* __restrict__ gstart,
                             unsigned short* __restrict__ gout) {
  int g = blockIdx.x, f = threadIdx.x;
  int s = gstart[g], e = gstart[g + 1];
  float sc = scale[f], sh = shift[f];
  float acc = 0.f;
  for (int r = s; r < e; r++) acc += fmaxf(h2f(v[(long long)r * 256 + f]) * sc + sh, 0.f);
  gout[(long long)g * 256 + f] = f2h16(acc / fmaxf((float)(e - s), 1.f));
}
__global__ void pred2_k(const unsigned short* __restrict__ p1, const void* __restrict__ Wp2,
                        const void* __restrict__ bp2, void* __restrict__ out, int G,
                        const int* __restrict__ flags) {
  int wf32 = flags[1];
  int idx = blockIdx.x * blockDim.x + threadIdx.x;
  if (idx >= G * 12) return;
  int g = idx / 12, t = idx - g * 12;
  float acc = lin(bp2, t, wf32);
  const unsigned short* row = p1 + (long long)g * 256;
  for (int k = 0; k < 256; k++) acc += h2f(row[k]) * lin(Wp2, k * 12 + t, wf32);
  if (wf32) ((float*)out)[idx] = acc;
  else      ((unsigned short*)out)[idx] = f2b(acc);
}

extern "C" void kernel_launch(void* const* d_in, const int* in_sizes, int n_in,
                              void* d_out, int out_size, void* d_ws, size_t ws_size,
                              hipStream_t stream) {
  int wb = -1;
  for (int i = 3; i + 15 < n_in; i++) {
    if (in_sizes[i] == 32768 && in_sizes[i + 1] == 256 && in_sizes[i + 2] == 65536 &&
        in_sizes[i + 3] == 256 && in_sizes[i + 4] == 256 && in_sizes[i + 5] == 256 &&
        in_sizes[i + 6] == 262144) { wb = i; break; }
  }
  if (wb < 0) wb = (n_in >= 20) ? 4 : 3;

  const void* x      = d_in[0];
  const int*  edge   = (const int*)d_in[1];
  const int*  batch  = (const int*)d_in[2];
  const void* W1_0   = d_in[wb + 0];
  const void* b1_0   = d_in[wb + 1];
  const void* W2_0   = d_in[wb + 2];
  const void* b2_0   = d_in[wb + 3];
  const void* gamma0 = d_in[wb + 4];
  const void* beta0  = d_in[wb + 5];
  const void* W1s    = d_in[wb + 6];
  const void* b1s    = d_in[wb + 7];
  const void* W2s    = d_in[wb + 8];
  const void* b2s    = d_in[wb + 9];
  const void* gammas = d_in[wb + 10];
  const void* betas  = d_in[wb + 11];
  const void* Wp1    = d_in[wb + 12];
  const void* bp1    = d_in[wb + 13];
  const void* Wp2    = d_in[wb + 14];
  const void* bp2    = d_in[wb + 15];

  const int N = in_sizes[0] / 128;
  const int E = in_sizes[1] / 2;
  const int G = out_size / 12;
  const int H = 256;

  char* w = (char*)d_ws;
  size_t off = 0;
  auto alloc = [&](size_t bytes) -> char* {
    char* p = w + off;
    off += (bytes + 255) & ~(size_t)255;
    return p;
  };
  unsigned short* bufX  = (unsigned short*)alloc((size_t)N * H * 2);
  unsigned short* bufY  = (unsigned short*)alloc((size_t)N * H * 2);  // xh parks at [0, N*128)
  unsigned short* w1_0t = (unsigned short*)alloc((size_t)128 * 256 * 2);
  unsigned short* w2_0t = (unsigned short*)alloc((size_t)256 * 256 * 2);
  unsigned short* w1st  = (unsigned short*)alloc((size_t)4 * 256 * 256 * 2);
  unsigned short* w2st  = (unsigned short*)alloc((size_t)4 * 256 * 256 * 2);
  unsigned short* wp1t  = (unsigned short*)alloc((size_t)256 * 256 * 2);
  int*   rowptr   = (int*)alloc((size_t)(N + 1) * 4);
  int*   cnt      = (int*)alloc((size_t)N * 4);
  int*   colidx   = (int*)alloc((size_t)E * 4);
  int*   partials = (int*)alloc(1024 * 4);
  float* gsum     = (float*)alloc(512 * 4);
  float* bnscale  = (float*)alloc(256 * 4);
  float* bnshift  = (float*)alloc(256 * 4);
  float* pg       = (float*)alloc(256 * 4);
  float* pb       = (float*)alloc(256 * 4);
  float* pb1      = (float*)alloc(256 * 4);
  float* pb2      = (float*)alloc(256 * 4);
  int*   gstart   = (int*)alloc((size_t)(G + 1) * 4);
  int*   flags    = (int*)alloc(256);
  unsigned short* gpool = (unsigned short*)alloc((size_t)G * H * 2);
  unsigned short* p1    = (unsigned short*)alloc((size_t)G * H * 2);
  (void)ws_size; (void)n_in;

  detect_k<<<1, 64, 0, stream>>>(edge, (const unsigned short*)x, flags);

  // x -> fp16 into bufY (dead once layer-0 gemm1 overwrites bufY)
  convert_k<<<(int)(((long long)N * 128 / 4 + 255) / 256), 256, 0, stream>>>(
      x, bufY, (long long)N * 128, flags);

  dim3 tb(32, 8);
  auto transpose = [&](const void* src, long long eoff, unsigned short* dst, int R, int C) {
    transpose_off_k<<<dim3((C + 31) / 32, (R + 31) / 32), tb, 0, stream>>>(src, eoff, dst, R, C, flags);
  };
  transpose(W1_0, 0, w1_0t, 128, 256);
  transpose(W2_0, 0, w2_0t, 256, 256);
  for (int i = 0; i < 4; i++) {
    transpose(W1s, (long long)i * 65536, w1st + i * 65536, 256, 256);
    transpose(W2s, (long long)i * 65536, w2st + i * 65536, 256, 256);
  }
  transpose(Wp1, 0, wp1t, 256, 256);

  // CSR
  zero_i32_k<<<(N + 255) / 256, 256, 0, stream>>>(cnt, N);
  hist_k<<<(E + 255) / 256, 256, 0, stream>>>(edge, E, cnt, flags);
  int NB = (N + SCAN_CHUNK - 1) / SCAN_CHUNK;
  scan1_k<<<NB, 256, 0, stream>>>(cnt, rowptr, partials, N);
  scan2_k<<<1, 256, 0, stream>>>(partials, NB);
  scan3_k<<<NB, 256, 0, stream>>>(rowptr, partials, N, E);
  zero_i32_k<<<(N + 255) / 256, 256, 0, stream>>>(cnt, N);
  fill_k<<<(E + 255) / 256, 256, 0, stream>>>(edge, E, rowptr, cnt, colidx, flags);
  graph_bounds_k<<<(G + 1 + 255) / 256, 256, 0, stream>>>(batch, N, G, gstart, flags);

  auto gemm = [&](const unsigned short* A, const unsigned short* Bt, const float* bias,
                  unsigned short* Cq, int M, int K, int relu) {
    gemm_k<<<dim3((M + 127) / 128, 2), 256, 0, stream>>>(A, Bt, bias, Cq, M, K, relu);
  };
  auto bnorm = [&](const unsigned short* v) {
    bn_stats_k<<<512, 256, 0, stream>>>(v, gsum, N);
    bn_finalize_k<<<1, 256, 0, stream>>>(gsum, pg, pb, N, bnscale, bnshift);
  };

  // ---- layer 0 ----
  prep_k<<<1, 256, 0, stream>>>(b1_0, b2_0, gamma0, beta0, 0, pb1, pb2, pg, pb, gsum, flags);
  gather_fused_k<16, 0><<<(N * 16 + 255) / 256, 256, 0, stream>>>(
      bufY, bnscale, bnshift, rowptr, colidx, bufX, N);
  gemm(bufX, w1_0t, pb1, bufY, N, 128, 1);
  gemm(bufY, w2_0t, pb2, bufX, N, 256, 0);
  bnorm(bufX);
  unsigned short* cur = bufX;  // pre-BN v0
  unsigned short* oth = bufY;
  // ---- layers 1..4 ----
  for (int i = 0; i < 4; i++) {
    prep_k<<<1, 256, 0, stream>>>(b1s, b2s, gammas, betas, i * 256, pb1, pb2, pg, pb, gsum, flags);
    gather_fused_k<32, 1><<<(N * 32 + 255) / 256, 256, 0, stream>>>(
        cur, bnscale, bnshift, rowptr, colidx, oth, N);
    gemm(oth, w1st + i * 65536, pb1, cur, N, 256, 1);
    gemm(cur, w2st + i * 65536, pb2, oth, N, 256, 0);
    bnorm(oth);
    unsigned short* t = cur; cur = oth; oth = t;  // v_i now in cur
  }

  // ---- pool + predictor ----
  copy256_k<<<1, 256, 0, stream>>>(bp1, 0, pb1, flags);
  pool_fused_k<<<G, 256, 0, stream>>>(cur, bnscale, bnshift, gstart, gpool);
  gemm(gpool, wp1t, pb1, p1, G, 256, 1);
  pred2_k<<<(G * 12 + 255) / 256, 256, 0, stream>>>(p1, Wp2, bp2, d_out, G, flags);
}

// Round 6
// 984.103 us; speedup vs baseline: 2.2213x; 1.1635x over previous
//
#include <hip/hip_runtime.h>

// GINModel on MI355X (gfx950). Round 6:
//  - gemm: LDS-staged coalesced C epilogue (fixes 2x write amplification seen
//    as WRITE_SIZE 100MB vs 51MB ideal in round-5 counters)
//  - BN stats fused into gemm2 epilogue (removes bn_stats_k entirely)
//  - padded LDS staging strides
// fp16 internal storage, fp32 accumulation, dual-width input hardening.

typedef __attribute__((ext_vector_type(4))) float f32x4;
typedef __attribute__((ext_vector_type(8))) _Float16 f16x8;

__device__ __forceinline__ float h2f(unsigned short u) {
  _Float16 h; __builtin_memcpy(&h, &u, 2); return (float)h;
}
__device__ __forceinline__ unsigned short f2h16(float f) {
  _Float16 h = (_Float16)f; unsigned short u; __builtin_memcpy(&u, &h, 2); return u;
}
__device__ __forceinline__ unsigned short f2b(float f) {  // fp32 -> bf16 RNE
  union { float f; unsigned int i; } c; c.f = f;
  unsigned int x = c.i;
  return (unsigned short)((x + 0x7fffu + ((x >> 16) & 1u)) >> 16);
}
__device__ __forceinline__ float lin(const void* p, long long i, int wf32) {
  if (wf32) return ((const float*)p)[i];
  union { unsigned int i; float f; } c;
  c.i = ((unsigned int)((const unsigned short*)p)[i]) << 16;
  return c.f;
}
__device__ __forceinline__ int ldidx(const int* p, long long i, int w64) {
  return w64 ? p[2 * i] : p[i];
}

// flags[0]=w64 (int64 indices), flags[1]=wf32 (fp32 floats)
__global__ void detect_k(const int* __restrict__ edge, const unsigned short* __restrict__ xa,
                         int* __restrict__ flags) {
  if (threadIdx.x != 0 || blockIdx.x != 0) return;
  int nzOdd = 0;
  for (int t = 0; t < 256; t++) if (edge[2 * t + 1] != 0) nzOdd++;
  flags[0] = (nzOdd == 0) ? 1 : 0;
  int plaus = 0;
  for (int t = 0; t < 64; t++) {
    unsigned short w = xa[2 * t];
    int e = (w >> 7) & 0xFF;
    if (w == 0 || (e >= 0x70 && e <= 0x85)) plaus++;
  }
  flags[1] = (plaus < 32) ? 1 : 0;
}

__global__ void zero_i32_k(int* __restrict__ p, int n) {
  int i = blockIdx.x * blockDim.x + threadIdx.x;
  if (i < n) p[i] = 0;
}

// per-layer prep: slice 4x256 params to fp32 + zero BN accumulators (512 f32)
__global__ void prep_k(const void* __restrict__ b1, const void* __restrict__ b2,
                       const void* __restrict__ gm, const void* __restrict__ bt, int eoff,
                       float* __restrict__ pb1, float* __restrict__ pb2,
                       float* __restrict__ pg, float* __restrict__ pb,
                       float* __restrict__ gsum, const int* __restrict__ flags) {
  int wf32 = flags[1], t = threadIdx.x;
  pb1[t] = lin(b1, (long long)eoff + t, wf32);
  pb2[t] = lin(b2, (long long)eoff + t, wf32);
  pg[t]  = lin(gm, (long long)eoff + t, wf32);
  pb[t]  = lin(bt, (long long)eoff + t, wf32);
  gsum[t] = 0.f; gsum[256 + t] = 0.f;
}
__global__ void copy256_k(const void* __restrict__ src, int eoff, float* __restrict__ dst,
                          const int* __restrict__ flags) {
  dst[threadIdx.x] = lin(src, (long long)eoff + threadIdx.x, flags[1]);
}

// input (R x C at element offset, dual width) -> fp16 transposed (C x R)
__global__ void transpose_off_k(const void* __restrict__ src, long long eoff,
                                unsigned short* __restrict__ dst, int R, int C,
                                const int* __restrict__ flags) {
  int wf32 = flags[1];
  __shared__ unsigned short t[32][33];
  int bx = blockIdx.x * 32, by = blockIdx.y * 32;
  int x = bx + threadIdx.x;
  for (int i = 0; i < 32; i += 8) {
    int y = by + threadIdx.y + i;
    if (y < R && x < C)
      t[threadIdx.y + i][threadIdx.x] = f2h16(lin(src, eoff + (long long)y * C + x, wf32));
  }
  __syncthreads();
  int x2 = by + threadIdx.x;
  for (int i = 0; i < 32; i += 8) {
    int y = bx + threadIdx.y + i;
    if (y < C && x2 < R) dst[(long long)y * R + x2] = t[threadIdx.x][threadIdx.y + i];
  }
}

// ---------------- CSR ----------------
__global__ void hist_k(const int* __restrict__ edge, int E, int* __restrict__ cnt,
                       const int* __restrict__ flags) {
  int w64 = flags[0];
  int e = blockIdx.x * blockDim.x + threadIdx.x;
  if (e < E) atomicAdd(&cnt[ldidx(edge, (long long)E + e, w64)], 1);
}
#define SCAN_CHUNK 1024
__global__ void scan1_k(const int* __restrict__ in, int* __restrict__ out,
                        int* __restrict__ partials, int n) {
  __shared__ int sh[256];
  int tid = threadIdx.x;
  int base = blockIdx.x * SCAN_CHUNK + tid * 4;
  int v[4]; int tsum = 0;
#pragma unroll
  for (int i = 0; i < 4; i++) { v[i] = (base + i < n) ? in[base + i] : 0; tsum += v[i]; }
  sh[tid] = tsum; __syncthreads();
  for (int off = 1; off < 256; off <<= 1) {
    int t = (tid >= off) ? sh[tid - off] : 0;
    __syncthreads();
    sh[tid] += t;
    __syncthreads();
  }
  int run = sh[tid] - tsum;
#pragma unroll
  for (int i = 0; i < 4; i++) { if (base + i < n) out[base + i] = run; run += v[i]; }
  if (tid == 255) partials[blockIdx.x] = sh[255];
}
__global__ void scan2_k(int* partials, int B) {
  __shared__ int sh[256];
  int tid = threadIdx.x;
  int orig = (tid < B) ? partials[tid] : 0;
  sh[tid] = orig; __syncthreads();
  for (int off = 1; off < 256; off <<= 1) {
    int t = (tid >= off) ? sh[tid - off] : 0;
    __syncthreads();
    sh[tid] += t;
    __syncthreads();
  }
  if (tid < B) partials[tid] = sh[tid] - orig;
}
__global__ void scan3_k(int* __restrict__ out, const int* __restrict__ partials,
                        int n, int total) {
  int base = blockIdx.x * SCAN_CHUNK + threadIdx.x * 4;
  int add = partials[blockIdx.x];
#pragma unroll
  for (int i = 0; i < 4; i++) { if (base + i < n) out[base + i] += add; }
  if (blockIdx.x == 0 && threadIdx.x == 0) out[n] = total;
}
__global__ void fill_k(const int* __restrict__ edge, int E, const int* __restrict__ rowptr,
                       int* __restrict__ cnt, int* __restrict__ colidx,
                       const int* __restrict__ flags) {
  int w64 = flags[0];
  int e = blockIdx.x * blockDim.x + threadIdx.x;
  if (e >= E) return;
  int s = ldidx(edge, e, w64);
  int d = ldidx(edge, (long long)E + e, w64);
  int p = atomicAdd(&cnt[d], 1);
  colidx[rowptr[d] + p] = s;
}
__global__ void graph_bounds_k(const int* __restrict__ b, int Nn, int G,
                               int* __restrict__ gstart, const int* __restrict__ flags) {
  int w64 = flags[0];
  int g = blockIdx.x * blockDim.x + threadIdx.x;
  if (g > G) return;
  int lo = 0, hi = Nn;
  while (lo < hi) {
    int mid = (lo + hi) >> 1;
    if (ldidx(b, mid, w64) < g) lo = mid + 1; else hi = mid;
  }
  gstart[g] = lo;
}

// x (dual width) -> fp16
__global__ void convert_k(const void* __restrict__ x, unsigned short* __restrict__ xh,
                          long long n, const int* __restrict__ flags) {
  int wf32 = flags[1];
  long long base = ((long long)blockIdx.x * blockDim.x + threadIdx.x) * 4;
  if (base >= n) return;
#pragma unroll
  for (int k = 0; k < 4; k++) xh[base + k] = f2h16(lin(x, base + k, wf32));
}

// fused aggregation: u[i] = hn(i) + sum_{j in nbrs(i)} hn(j)
// hn = APPLY ? relu(v*scale+shift) : v.  LPN lanes per node, 8 fp16 per lane.
template <int LPN, int APPLY>
__global__ void gather_fused_k(const unsigned short* __restrict__ src,
                               const float* __restrict__ scale, const float* __restrict__ shift,
                               const int* __restrict__ rowptr, const int* __restrict__ colidx,
                               unsigned short* __restrict__ u, int Nn) {
  const int F = LPN * 8;
  int gid = blockIdx.x * blockDim.x + threadIdx.x;
  int node = gid / LPN;
  if (node >= Nn) return;
  int fb = (gid % LPN) * 8;
  float sc[8], sh[8];
  if (APPLY) {
#pragma unroll
    for (int k = 0; k < 8; k++) { sc[k] = scale[fb + k]; sh[k] = shift[fb + k]; }
  }
  float acc[8];
  {
    uint4 raw = *(const uint4*)(src + (long long)node * F + fb);
    unsigned int ws[4] = {raw.x, raw.y, raw.z, raw.w};
#pragma unroll
    for (int k = 0; k < 8; k++) {
      float xv = h2f((unsigned short)((ws[k >> 1] >> ((k & 1) * 16)) & 0xffff));
      acc[k] = APPLY ? fmaxf(xv * sc[k] + sh[k], 0.f) : xv;
    }
  }
  int s = rowptr[node], e = rowptr[node + 1];
  for (int j = s; j < e; j++) {
    long long nb = colidx[j];
    uint4 raw = *(const uint4*)(src + nb * F + fb);
    unsigned int ws[4] = {raw.x, raw.y, raw.z, raw.w};
#pragma unroll
    for (int k = 0; k < 8; k++) {
      float xv = h2f((unsigned short)((ws[k >> 1] >> ((k & 1) * 16)) & 0xffff));
      acc[k] += APPLY ? fmaxf(xv * sc[k] + sh[k], 0.f) : xv;
    }
  }
  uint4 o;
  unsigned int wo[4];
#pragma unroll
  for (int p = 0; p < 4; p++)
    wo[p] = (unsigned int)f2h16(acc[2 * p]) | ((unsigned int)f2h16(acc[2 * p + 1]) << 16);
  o.x = wo[0]; o.y = wo[1]; o.z = wo[2]; o.w = wo[3];
  *(uint4*)(u + (long long)node * F + fb) = o;
}

// MFMA fp16 GEMM, K-tile register prefetch, LDS-staged coalesced epilogue,
// optional fused BN stats (gsum != nullptr: atomicAdd per-column sum/sumsq).
// C(MxN=256) = act(A(MxK) @ W + bias_f32); Bt = W^T (256 x K).
// Tile 128x128 (grid.y=2 halves of N), BK=32, 4 waves (2x2 of 64x64).
#define SA 40    // padded A/B staging stride (fp16)
#define SP 136   // padded C-tile stride (fp16)
__global__ __launch_bounds__(256) void gemm_k(
    const unsigned short* __restrict__ A, const unsigned short* __restrict__ Bt,
    const float* __restrict__ bias, unsigned short* __restrict__ C,
    int M, int K, int relu, float* __restrict__ gsum) {
  __shared__ __align__(16) unsigned short smem[128 * SP];  // 34816 B; unioned
  unsigned short* As = smem;                                // 128 x SA
  unsigned short* Bs = smem + 128 * SA;                     // 128 x SA
  int m0 = blockIdx.x * 128, n0 = blockIdx.y * 128;
  int tid = threadIdx.x;
  int wave = tid >> 6, lane = tid & 63;
  int wm = (wave >> 1) * 64, wn = (wave & 1) * 64;
  int lrow = lane & 15, lq = lane >> 4;
  f32x4 acc[4][4] = {};
  int ktiles = K >> 5;
  int srow = tid >> 2;              // staging row 0..63 (and +64)
  int ch8 = (tid & 3) << 3;         // staging col chunk (fp16 elems)
  int rowA0 = m0 + srow;      rowA0 = rowA0 < M ? rowA0 : M - 1;
  int rowA1 = m0 + srow + 64; rowA1 = rowA1 < M ? rowA1 : M - 1;
  const unsigned short* pa0 = A + (long long)rowA0 * K + ch8;
  const unsigned short* pa1 = A + (long long)rowA1 * K + ch8;
  const unsigned short* pq0 = Bt + (long long)(n0 + srow) * K + ch8;
  const unsigned short* pq1 = Bt + (long long)(n0 + srow + 64) * K + ch8;
  uint4 va0 = *(const uint4*)pa0, va1 = *(const uint4*)pa1;
  uint4 vb0 = *(const uint4*)pq0, vb1 = *(const uint4*)pq1;
  int lo0 = srow * SA + ch8, lo1 = (srow + 64) * SA + ch8;
  for (int kt = 0; kt < ktiles; ++kt) {
    __syncthreads();
    *(uint4*)(As + lo0) = va0;
    *(uint4*)(As + lo1) = va1;
    *(uint4*)(Bs + lo0) = vb0;
    *(uint4*)(Bs + lo1) = vb1;
    __syncthreads();
    f16x8 af[4], bf[4];
#pragma unroll
    for (int r = 0; r < 4; r++)
      af[r] = *(const f16x8*)(As + (wm + 16 * r + lrow) * SA + lq * 8);
#pragma unroll
    for (int c = 0; c < 4; c++)
      bf[c] = *(const f16x8*)(Bs + (wn + 16 * c + lrow) * SA + lq * 8);
    if (kt + 1 < ktiles) {  // prefetch next K-tile; overlaps MFMA below
      int kb = (kt + 1) << 5;
      va0 = *(const uint4*)(pa0 + kb); va1 = *(const uint4*)(pa1 + kb);
      vb0 = *(const uint4*)(pq0 + kb); vb1 = *(const uint4*)(pq1 + kb);
    }
#pragma unroll
    for (int r = 0; r < 4; r++)
#pragma unroll
      for (int c = 0; c < 4; c++)
        acc[r][c] = __builtin_amdgcn_mfma_f32_16x16x32_f16(af[r], bf[c], acc[r][c], 0, 0, 0);
  }
  // ---- epilogue: stage bias+act tile to LDS, then coalesced uint4 stores ----
  __syncthreads();                     // done with As/Bs; reuse smem as C tile
  unsigned short* Ct = smem;           // 128 x SP
#pragma unroll
  for (int c = 0; c < 4; c++) {
    int col = wn + 16 * c + lrow;
    float bv = bias[n0 + col];
#pragma unroll
    for (int r = 0; r < 4; r++) {
      int rbase = wm + 16 * r + lq * 4;
#pragma unroll
      for (int i = 0; i < 4; i++) {
        float v = acc[r][c][i] + bv;
        if (relu) v = fmaxf(v, 0.f);
        Ct[(rbase + i) * SP + col] = f2h16(v);
      }
    }
  }
  __syncthreads();
  int c16 = tid & 15, g = tid >> 4;    // 16 col-chunks x 16 row-groups
  float s8[8] = {}, q8[8] = {};
  bool dostats = (gsum != nullptr);
#pragma unroll
  for (int i = 0; i < 8; i++) {
    int row = g + i * 16;
    int grow = m0 + row;
    uint4 vw = *(const uint4*)(Ct + row * SP + c16 * 8);
    if (grow < M) {
      *(uint4*)(C + (long long)grow * 256 + n0 + c16 * 8) = vw;
      if (dostats) {
        unsigned int ws[4] = {vw.x, vw.y, vw.z, vw.w};
#pragma unroll
        for (int k = 0; k < 8; k++) {
          float xv = h2f((unsigned short)((ws[k >> 1] >> ((k & 1) * 16)) & 0xffff));
          s8[k] += xv; q8[k] += xv * xv;
        }
      }
    }
  }
  if (dostats) {
    float* shf = (float*)smem;         // 128*17 floats = 8.7 KB (swizzled)
    __syncthreads();
#pragma unroll
    for (int k = 0; k < 8; k++) shf[(c16 * 8 + k) * 17 + g] = s8[k];
    __syncthreads();
    if (tid < 128) {
      float t = 0.f;
#pragma unroll
      for (int gg = 0; gg < 16; gg++) t += shf[tid * 17 + gg];
      atomicAdd(&gsum[n0 + tid], t);
    }
    __syncthreads();
#pragma unroll
    for (int k = 0; k < 8; k++) shf[(c16 * 8 + k) * 17 + g] = q8[k];
    __syncthreads();
    if (tid < 128) {
      float t = 0.f;
#pragma unroll
      for (int gg = 0; gg < 16; gg++) t += shf[tid * 17 + gg];
      atomicAdd(&gsum[256 + n0 + tid], t);
    }
  }
}

__global__ void bn_finalize_k(const float* __restrict__ gsum,
                              const float* __restrict__ pg, const float* __restrict__ pb,
                              int Nn, float* __restrict__ scale, float* __restrict__ shift) {
  int f = threadIdx.x;
  float inv = 1.f / (float)Nn;
  float mean = gsum[f] * inv;
  float var = fmaxf(gsum[256 + f] * inv - mean * mean, 0.f);
  float sc = pg[f] * rsqrtf(var + 1e-5f);
  scale[f] = sc;
  shift[f] = pb[f] - mean * sc;
}

// fused pool: mean over graph rows of relu(v*sc+sh)
__global__ void pool_fused_k(const unsigned short* __restrict__ v, const float* __restrict__ scale,
                             const float* __restrict__ shift, const int* __restrict__ gstart,
                             unsigned short* __restrict__ gout) {
  int g = blockIdx.x, f = threadIdx.x;
  int s = gstart[g], e = gstart[g + 1];
  float sc = scale[f], sh = shift[f];
  float acc = 0.f;
  for (int r = s; r < e; r++) acc += fmaxf(h2f(v[(long long)r * 256 + f]) * sc + sh, 0.f);
  gout[(long long)g * 256 + f] = f2h16(acc / fmaxf((float)(e - s), 1.f));
}
__global__ void pred2_k(const unsigned short* __restrict__ p1, const void* __restrict__ Wp2,
                        const void* __restrict__ bp2, void* __restrict__ out, int G,
                        const int* __restrict__ flags) {
  int wf32 = flags[1];
  int idx = blockIdx.x * blockDim.x + threadIdx.x;
  if (idx >= G * 12) return;
  int g = idx / 12, t = idx - g * 12;
  float acc = lin(bp2, t, wf32);
  const unsigned short* row = p1 + (long long)g * 256;
  for (int k = 0; k < 256; k++) acc += h2f(row[k]) * lin(Wp2, k * 12 + t, wf32);
  if (wf32) ((float*)out)[idx] = acc;
  else      ((unsigned short*)out)[idx] = f2b(acc);
}

extern "C" void kernel_launch(void* const* d_in, const int* in_sizes, int n_in,
                              void* d_out, int out_size, void* d_ws, size_t ws_size,
                              hipStream_t stream) {
  int wb = -1;
  for (int i = 3; i + 15 < n_in; i++) {
    if (in_sizes[i] == 32768 && in_sizes[i + 1] == 256 && in_sizes[i + 2] == 65536 &&
        in_sizes[i + 3] == 256 && in_sizes[i + 4] == 256 && in_sizes[i + 5] == 256 &&
        in_sizes[i + 6] == 262144) { wb = i; break; }
  }
  if (wb < 0) wb = (n_in >= 20) ? 4 : 3;

  const void* x      = d_in[0];
  const int*  edge   = (const int*)d_in[1];
  const int*  batch  = (const int*)d_in[2];
  const void* W1_0   = d_in[wb + 0];
  const void* b1_0   = d_in[wb + 1];
  const void* W2_0   = d_in[wb + 2];
  const void* b2_0   = d_in[wb + 3];
  const void* gamma0 = d_in[wb + 4];
  const void* beta0  = d_in[wb + 5];
  const void* W1s    = d_in[wb + 6];
  const void* b1s    = d_in[wb + 7];
  const void* W2s    = d_in[wb + 8];
  const void* b2s    = d_in[wb + 9];
  const void* gammas = d_in[wb + 10];
  const void* betas  = d_in[wb + 11];
  const void* Wp1    = d_in[wb + 12];
  const void* bp1    = d_in[wb + 13];
  const void* Wp2    = d_in[wb + 14];
  const void* bp2    = d_in[wb + 15];

  const int N = in_sizes[0] / 128;
  const int E = in_sizes[1] / 2;
  const int G = out_size / 12;
  const int H = 256;

  char* w = (char*)d_ws;
  size_t off = 0;
  auto alloc = [&](size_t bytes) -> char* {
    char* p = w + off;
    off += (bytes + 255) & ~(size_t)255;
    return p;
  };
  unsigned short* bufX  = (unsigned short*)alloc((size_t)N * H * 2);
  unsigned short* bufY  = (unsigned short*)alloc((size_t)N * H * 2);  // xh parks here first
  unsigned short* w1_0t = (unsigned short*)alloc((size_t)128 * 256 * 2);
  unsigned short* w2_0t = (unsigned short*)alloc((size_t)256 * 256 * 2);
  unsigned short* w1st  = (unsigned short*)alloc((size_t)4 * 256 * 256 * 2);
  unsigned short* w2st  = (unsigned short*)alloc((size_t)4 * 256 * 256 * 2);
  unsigned short* wp1t  = (unsigned short*)alloc((size_t)256 * 256 * 2);
  int*   rowptr   = (int*)alloc((size_t)(N + 1) * 4);
  int*   cnt      = (int*)alloc((size_t)N * 4);
  int*   colidx   = (int*)alloc((size_t)E * 4);
  int*   partials = (int*)alloc(1024 * 4);
  float* gsum     = (float*)alloc(512 * 4);
  float* bnscale  = (float*)alloc(256 * 4);
  float* bnshift  = (float*)alloc(256 * 4);
  float* pg       = (float*)alloc(256 * 4);
  float* pb       = (float*)alloc(256 * 4);
  float* pb1      = (float*)alloc(256 * 4);
  float* pb2      = (float*)alloc(256 * 4);
  int*   gstart   = (int*)alloc((size_t)(G + 1) * 4);
  int*   flags    = (int*)alloc(256);
  unsigned short* gpool = (unsigned short*)alloc((size_t)G * H * 2);
  unsigned short* p1    = (unsigned short*)alloc((size_t)G * H * 2);
  (void)ws_size; (void)n_in;

  detect_k<<<1, 64, 0, stream>>>(edge, (const unsigned short*)x, flags);

  // x -> fp16 into bufY (dead once layer-0 gemm1 overwrites bufY)
  convert_k<<<(int)(((long long)N * 128 / 4 + 255) / 256), 256, 0, stream>>>(
      x, bufY, (long long)N * 128, flags);

  dim3 tb(32, 8);
  auto transpose = [&](const void* src, long long eoff, unsigned short* dst, int R, int C) {
    transpose_off_k<<<dim3((C + 31) / 32, (R + 31) / 32), tb, 0, stream>>>(src, eoff, dst, R, C, flags);
  };
  transpose(W1_0, 0, w1_0t, 128, 256);
  transpose(W2_0, 0, w2_0t, 256, 256);
  for (int i = 0; i < 4; i++) {
    transpose(W1s, (long long)i * 65536, w1st + i * 65536, 256, 256);
    transpose(W2s, (long long)i * 65536, w2st + i * 65536, 256, 256);
  }
  transpose(Wp1, 0, wp1t, 256, 256);

  // CSR
  zero_i32_k<<<(N + 255) / 256, 256, 0, stream>>>(cnt, N);
  hist_k<<<(E + 255) / 256, 256, 0, stream>>>(edge, E, cnt, flags);
  int NB = (N + SCAN_CHUNK - 1) / SCAN_CHUNK;
  scan1_k<<<NB, 256, 0, stream>>>(cnt, rowptr, partials, N);
  scan2_k<<<1, 256, 0, stream>>>(partials, NB);
  scan3_k<<<NB, 256, 0, stream>>>(rowptr, partials, N, E);
  zero_i32_k<<<(N + 255) / 256, 256, 0, stream>>>(cnt, N);
  fill_k<<<(E + 255) / 256, 256, 0, stream>>>(edge, E, rowptr, cnt, colidx, flags);
  graph_bounds_k<<<(G + 1 + 255) / 256, 256, 0, stream>>>(batch, N, G, gstart, flags);

  auto gemm = [&](const unsigned short* A, const unsigned short* Bt, const float* bias,
                  unsigned short* Cq, int M, int K, int relu, float* stats) {
    gemm_k<<<dim3((M + 127) / 128, 2), 256, 0, stream>>>(A, Bt, bias, Cq, M, K, relu, stats);
  };

  // ---- layer 0 ----
  prep_k<<<1, 256, 0, stream>>>(b1_0, b2_0, gamma0, beta0, 0, pb1, pb2, pg, pb, gsum, flags);
  gather_fused_k<16, 0><<<(N * 16 + 255) / 256, 256, 0, stream>>>(
      bufY, bnscale, bnshift, rowptr, colidx, bufX, N);
  gemm(bufX, w1_0t, pb1, bufY, N, 128, 1, nullptr);
  gemm(bufY, w2_0t, pb2, bufX, N, 256, 0, gsum);   // v0 + fused BN stats
  bn_finalize_k<<<1, 256, 0, stream>>>(gsum, pg, pb, N, bnscale, bnshift);
  unsigned short* cur = bufX;  // pre-BN v0
  unsigned short* oth = bufY;
  // ---- layers 1..4 ----
  for (int i = 0; i < 4; i++) {
    prep_k<<<1, 256, 0, stream>>>(b1s, b2s, gammas, betas, i * 256, pb1, pb2, pg, pb, gsum, flags);
    gather_fused_k<32, 1><<<(N * 32 + 255) / 256, 256, 0, stream>>>(
        cur, bnscale, bnshift, rowptr, colidx, oth, N);
    gemm(oth, w1st + i * 65536, pb1, cur, N, 256, 1, nullptr);
    gemm(cur, w2st + i * 65536, pb2, oth, N, 256, 0, gsum);  // v_i + BN stats
    bn_finalize_k<<<1, 256, 0, stream>>>(gsum, pg, pb, N, bnscale, bnshift);
    unsigned short* t = cur; cur = oth; oth = t;  // v_i now in cur
  }

  // ---- pool + predictor ----
  copy256_k<<<1, 256, 0, stream>>>(bp1, 0, pb1, flags);
  pool_fused_k<<<G, 256, 0, stream>>>(cur, bnscale, bnshift, gstart, gpool);
  gemm(gpool, wp1t, pb1, p1, G, 256, 1, nullptr);
  pred2_k<<<(G * 12 + 255) / 256, 256, 0, stream>>>(p1, Wp2, bp2, d_out, G, flags);
}